// Round 10
// baseline (764.149 us; speedup 1.0000x reference)
//
#include <hip/hip_runtime.h>
#include <math.h>

// ---------------- constants ----------------
#define NPIX 32768            // 2 * 128 * 128
#define OUT_DZ 0
#define OUT_BLUR 18432
#define OUT_LD 51200
#define OUT_REG 51201
#define OUT_TV 51202

__constant__ int d_cin[18] = {512,512,512,512,512,512,512,512,256,256,128,128,64,64,32,32,16,16};
__constant__ int d_H[18]   = {4,  4,  8,  16, 32, 32, 64, 128,256,256,256,256,256,256,256,256,256,256};

struct FPtrs { const float* f[18]; };

// ws layout (float offsets)
#define WS_HA     0        // 7168
#define WS_HB     7168     // 7168
#define WS_ST     14336    // 8192
#define WS_CN     22528    // 48
#define WS_BIASP  22576    // 18 (pad to 22656)
#define WS_V      22656    // 9216
#define WS_CHOICE 31872    // 32768 ints
#define WS_PART   64640    // 18*32768 = 589824
#define WS_EACH   654464   // 32768 (unused now)
#define WS_SUMS   687232   // 128*20
#define WS_CNTS   689792   // 128*20 ints
#define WS_CNTR   692352   // 8 unsigned barrier counters

#define WAITVM(N) asm volatile("s_waitcnt vmcnt(" #N ")" ::: "memory")

// device-scope grid barrier (all blocks must be co-resident)
__device__ __forceinline__ void gridbar(unsigned* cnt, unsigned expected)
{
    __threadfence();                 // release my stores device-wide
    __syncthreads();
    if (threadIdx.x == 0) {
        __hip_atomic_fetch_add(cnt, 1u, __ATOMIC_ACQ_REL, __HIP_MEMORY_SCOPE_AGENT);
        while (__hip_atomic_load(cnt, __ATOMIC_ACQUIRE, __HIP_MEMORY_SCOPE_AGENT) < expected)
            __builtin_amdgcn_s_sleep(2);
    }
    __syncthreads();
    __threadfence();                 // acquire others' stores
}

// ---------------- k_pre: vfold (19 blocks) + RMS norm (14 blocks) + resets ----------------
__global__ __launch_bounds__(512) void k_pre(
    const float* __restrict__ afw, const float* __restrict__ afb,
    const float* __restrict__ aw,  const float* __restrict__ ab,
    const float* __restrict__ alw, const float* __restrict__ istate,
    float* __restrict__ v, float* __restrict__ biasp,
    float* __restrict__ st, float* __restrict__ cn,
    const float* __restrict__ x, float* __restrict__ h,
    unsigned* __restrict__ cntr, float* __restrict__ out)
{
    __shared__ float red[512];
    __shared__ float scale;
    int bid = blockIdx.x;
    int tid = threadIdx.x;
    if (bid == 19) {
        if (tid == 0) out[OUT_TV] = 0.0f;
        if (tid < 8) cntr[tid] = 0u;
    }
    if (bid < 18) {
        int t = bid;
        int cin = d_cin[t];
        const float* w  = (t==0) ? afw : aw + (size_t)(t-1)*32*512;
        const float* bb = (t==0) ? afb : ab + (t-1)*32;
        float sc = (1.0f/sqrtf((float)cin)) * (1.0f/24.0f);
        if (tid < cin) {
            float s = 0.0f;
            #pragma unroll 8
            for (int o = 0; o < 32; o++) s += alw[t*32+o] * w[o*512 + tid];
            v[t*512 + tid] = s * sc;
        }
        if (tid == 0) {
            float s = 0.0f;
            for (int o = 0; o < 32; o++) s += alw[t*32+o] * bb[o];
            biasp[t] = s * (1.0f/24.0f);
        }
    } else if (bid == 18) {
        if (tid < 512) {
            #pragma unroll
            for (int j = 0; j < 10; j++) st[tid*16 + j] = -2.0f * istate[j*576 + tid];
        }
        if (tid < 10) {
            int j = tid;
            float n = 0.0f, s1 = 0.0f, s2 = 0.0f;
            for (int k = 0; k < 576; k++) { float sv = istate[j*576+k]; n += sv*sv; }
            for (int k = 512; k < 544; k++) s1 += istate[j*576+k];
            for (int k = 544; k < 576; k++) s2 += istate[j*576+k];
            cn[j] = n; cn[16+j] = -2.0f*s1; cn[32+j] = -2.0f*s2;
        }
    } else {
        int r = bid - 19;             // 0..13 (b*7+c)
        int b = r / 7, c = r % 7;
        const float* xr = x + ((size_t)b*18 + c)*512;
        float v0 = xr[tid];
        red[tid] = v0*v0; __syncthreads();
        for (int s = 256; s; s >>= 1) { if (tid < s) red[tid] += red[tid+s]; __syncthreads(); }
        if (tid == 0) scale = 1.0f / sqrtf(red[0]*(1.0f/512.0f) + 1e-8f);
        __syncthreads();
        h[r*512 + tid] = v0*scale;
    }
}

// ---------------- k_map: 3 fused MLP layers (grid barrier) + dz zero-tail + lossdelta ----------------
__global__ __launch_bounds__(256, 4) void k_map(
    const float* __restrict__ mw, const float* __restrict__ mb,
    float* __restrict__ hA, float* __restrict__ hB,
    unsigned* __restrict__ cnt, float* __restrict__ out)
{
    __shared__ float red[256];
    int bid = blockIdx.x, tid = threadIdx.x;
    int wave = bid*4 + (tid >> 6);
    int lane = tid & 63;
    int c = wave >> 9, o = wave & 511;
    #pragma unroll
    for (int layer = 0; layer < 3; layer++) {
        const float* hin  = (layer & 1) ? hB : hA;   // l0: hA->hB, l1: hB->hA, l2: hA->hB
        float*       hout = (layer & 1) ? hA : hB;
        const float* wrow = mw + (((size_t)(c*3 + layer)*512 + o) << 9) + lane*8;
        float4 w0 = *(const float4*)wrow;
        float4 w1 = *(const float4*)(wrow + 4);
        const float* h0 = hin + (size_t)c*512 + lane*8;
        const float* h1 = hin + (size_t)(7 + c)*512 + lane*8;
        float4 a0 = *(const float4*)h0, a1 = *(const float4*)(h0+4);
        float4 b0 = *(const float4*)h1, b1 = *(const float4*)(h1+4);
        float d0 = a0.x*w0.x + a0.y*w0.y + a0.z*w0.z + a0.w*w0.w
                 + a1.x*w1.x + a1.y*w1.y + a1.z*w1.z + a1.w*w1.w;
        float d1 = b0.x*w0.x + b0.y*w0.y + b0.z*w0.z + b0.w*w0.w
                 + b1.x*w1.x + b1.y*w1.y + b1.z*w1.z + b1.w*w1.w;
        #pragma unroll
        for (int m = 32; m; m >>= 1) { d0 += __shfl_xor(d0, m); d1 += __shfl_xor(d1, m); }
        if (lane == 0) {
            const float wsc = (float)(0.1/22.62741699796952);
            const float rt2 = 1.41421356237309515f;
            float bias = mb[(c*3 + layer)*512 + o] * 0.1f;
            float z0 = d0*wsc + bias; z0 = (z0 > 0.0f ? z0 : 0.2f*z0) * rt2;
            float z1 = d1*wsc + bias; z1 = (z1 > 0.0f ? z1 : 0.2f*z1) * rt2;
            hout[(size_t)c*512 + o] = z0;
            hout[(size_t)(7 + c)*512 + o] = z1;
            if (layer == 2) {
                out[OUT_DZ + ((size_t)0*18 + c)*512 + o] = z0;
                out[OUT_DZ + ((size_t)1*18 + c)*512 + o] = z1;
            }
        }
        gridbar(&cnt[layer], 896u);
    }
    // post-barrier: hB is the final mapper output
    if (bid < 44) {
        int z = bid*256 + tid;
        if (z < 11264) {
            int b = z / (11*512), rem = z % (11*512);
            out[OUT_DZ + (size_t)b*18*512 + 7*512 + rem] = 0.0f;
        }
    } else if (bid == 44) {
        float total = 0.0f;
        for (int r = 0; r < 14; r++) {
            float v0 = hB[r*512 + tid], v1 = hB[r*512 + 256 + tid];
            red[tid] = v0*v0 + v1*v1; __syncthreads();
            for (int s = 128; s; s >>= 1) { if (tid < s) red[tid] += red[tid+s]; __syncthreads(); }
            if (tid == 0) total += sqrtf(red[0]);
            __syncthreads();
        }
        if (tid == 0) out[OUT_LD] = total * (1.0f/14.0f);
    }
}

// ---------------- MEGA: heavy(1408) + assign(512) + light(448) interleaved ----------------
__global__ __launch_bounds__(256) void k_mega(FPtrs fp, const float* __restrict__ v,
    const float* __restrict__ blend, const float* __restrict__ st,
    const float* __restrict__ cn, int* __restrict__ choice,
    float* __restrict__ partial)
{
    __shared__ float smem[16896];   // 67584 B
    int bid = blockIdx.x;
    int tid = threadIdx.x;
    int mk = bid / 37, mr = bid % 37;
    if (mr < 22) {
        // ================= HEAVY (R8-validated counted-vmcnt pipeline) =================
        int hid = mk*22 + mr;
        float (*buf)[4096] = (float(*)[4096])smem;
        float* vsh = smem + 16384;
        int t, b, rblk;
        if (hid < 128) { t = 7; b = hid >> 6; rblk = hid & 63; }
        else { int idx = hid - 128; t = 8 + (idx >> 7); int sub = idx & 127; b = sub >> 6; rblk = sub & 63; }
        int ch = d_cin[t];
        int H  = d_H[t];
        int y0 = rblk*2;
        int w = tid >> 6, lane = tid & 63;
        const float* base = fp.f[t] + (size_t)b*ch*(size_t)H*H;
        for (int i = tid; i < ch; i += 256) vsh[i] = v[t*512 + i];
        __syncthreads();

        int NP = (H == 128) ? (ch >> 4) : (ch >> 3);
        int S = (NP < 3) ? NP : 3;
        for (int q = 0; q < S; q++) {
            if (H == 256) {
                #pragma unroll
                for (int k = 0; k < 2; k++) {
                    int cl = 2*w + k;
                    const float* srcc = base + (size_t)(q*8 + cl)*65536 + (size_t)(2*y0)*256 + lane*4;
                    __builtin_amdgcn_global_load_lds(srcc,       &buf[q][(cl*2    )*256], 16, 0, 0);
                    __builtin_amdgcn_global_load_lds(srcc + 512, &buf[q][(cl*2 + 1)*256], 16, 0, 0);
                }
            } else {
                #pragma unroll
                for (int k = 0; k < 4; k++) {
                    int cl = 4*w + k;
                    const float* srcc = base + (size_t)(q*16 + cl)*16384 + (size_t)y0*128 + lane*4;
                    __builtin_amdgcn_global_load_lds(srcc, &buf[q][cl*256], 16, 0, 0);
                }
            }
        }
        int r = tid >> 7, x = tid & 127;
        float acc = 0.0f;
        for (int p = 0; p < NP; p++) {
            int ahead = S - p - 1;
            if (ahead >= 2)      { WAITVM(8); }
            else if (ahead == 1) { WAITVM(4); }
            else                 { WAITVM(0); }
            __builtin_amdgcn_sched_barrier(0);
            __builtin_amdgcn_s_barrier();
            __builtin_amdgcn_sched_barrier(0);
            if (S < NP) {
                int q = S & 3;
                if (H == 256) {
                    #pragma unroll
                    for (int k = 0; k < 2; k++) {
                        int cl = 2*w + k;
                        const float* srcc = base + (size_t)(S*8 + cl)*65536 + (size_t)(2*y0)*256 + lane*4;
                        __builtin_amdgcn_global_load_lds(srcc,       &buf[q][(cl*2    )*256], 16, 0, 0);
                        __builtin_amdgcn_global_load_lds(srcc + 512, &buf[q][(cl*2 + 1)*256], 16, 0, 0);
                    }
                } else {
                    #pragma unroll
                    for (int k = 0; k < 4; k++) {
                        int cl = 4*w + k;
                        const float* srcc = base + (size_t)(S*16 + cl)*16384 + (size_t)y0*128 + lane*4;
                        __builtin_amdgcn_global_load_lds(srcc, &buf[q][cl*256], 16, 0, 0);
                    }
                }
                S++;
            }
            __builtin_amdgcn_sched_barrier(0);
            const float* bp = buf[p & 3];
            if (H == 256) {
                int cb = p*8;
                #pragma unroll
                for (int cp = 0; cp < 8; cp++)
                    acc = fmaf(bp[(cp*2 + r)*256 + 2*x], vsh[cb + cp], acc);
            } else {
                int cb = p*16;
                #pragma unroll
                for (int cp = 0; cp < 16; cp++)
                    acc = fmaf(bp[cp*256 + r*128 + x], vsh[cb + cp], acc);
            }
        }
        partial[(size_t)t*NPIX + b*16384 + (size_t)(y0 + r)*128 + x] = acc;
    } else if (mr < 30) {
        // ================= ASSIGN (R4-validated split-K) =================
        int aid = mk*8 + (mr - 22);
        float* gsh = smem;
        int csub = __builtin_amdgcn_readfirstlane(tid >> 6);
        int pl = tid & 63;
        int p = aid*64 + pl;
        int b = p >> 14, rem = p & 16383;
        float g[10] = {0,0,0,0,0,0,0,0,0,0};
        const float* src = blend + ((size_t)b*512 + csub*128)*16384 + rem;
        const float* stc = st + csub*128*16;
        for (int c0 = 0; c0 < 128; c0 += 8) {
            float q[8];
            #pragma unroll
            for (int u = 0; u < 8; u++) q[u] = src[(size_t)(c0+u) << 14];
            #pragma unroll
            for (int u = 0; u < 8; u++) {
                #pragma unroll
                for (int j = 0; j < 10; j++) g[j] = fmaf(q[u], stc[(c0+u)*16 + j], g[j]);
            }
        }
        #pragma unroll
        for (int j = 0; j < 10; j++) gsh[tid*10 + j] = g[j];
        __syncthreads();
        if (tid < 64) {
            int pp = aid*64 + tid;
            int bb = pp >> 14, rr = pp & 16383, y = rr >> 7, x = rr & 127;
            float cx = (float)x * (float)(2.0/127.0) - 1.0f;
            float cy = (float)y * (float)(2.0/127.0) - 1.0f;
            float gt[10];
            #pragma unroll
            for (int j = 0; j < 10; j++) {
                gt[j] = cn[j] + cn[16+j]*cx + cn[32+j]*cy
                      + gsh[tid*10 + j] + gsh[(64+tid)*10 + j]
                      + gsh[(128+tid)*10 + j] + gsh[(192+tid)*10 + j];
            }
            int best = 0; float bg = gt[0];
            #pragma unroll
            for (int j = 1; j < 10; j++) if (gt[j] < bg) { bg = gt[j]; best = j; }
            choice[pp] = bb*10 + best;
        }
    } else {
        // ================= LIGHT (validated gather) =================
        int lid = mk*7 + (mr - 30);
        float* vsh = smem;
        int t  = lid >> 6;
        int nc = d_cin[t];
        int H  = d_H[t];
        for (int i = tid; i < nc; i += 256) vsh[i] = v[t*512 + i];
        __syncthreads();
        int w = tid >> 6, lane = tid & 63;
        int px = lid & 63;
        int pbase = px*512;
        int b = pbase >> 14;
        int y = ((pbase & 16383) >> 7) + w;
        const float* base = fp.f[t] + (size_t)b*nc*(size_t)(H*H);
        float a0 = 0.0f, a1 = 0.0f;
        if (H == 64) {
            const float* src = base + (size_t)(y >> 1)*64 + lane;
            for (int cc = 0; cc < nc; cc += 8) {
                float q[8];
                #pragma unroll
                for (int u = 0; u < 8; u++) q[u] = src[(size_t)(cc+u)*4096];
                #pragma unroll
                for (int u = 0; u < 8; u++) {
                    float vv = vsh[cc+u];
                    a0 = fmaf(q[u], vv, a0); a1 = fmaf(q[u], vv, a1);
                }
            }
        } else {
            int x0 = 2*lane, x1 = 2*lane + 1;
            int sy = (y*H) >> 7, sx0 = (x0*H) >> 7, sx1 = (x1*H) >> 7;
            const float* src = base + (size_t)sy*H;
            size_t HH = (size_t)H*H;
            for (int cc = 0; cc < nc; cc += 8) {
                float q0[8], q1[8];
                #pragma unroll
                for (int u = 0; u < 8; u++) {
                    q0[u] = src[(size_t)(cc+u)*HH + sx0];
                    q1[u] = src[(size_t)(cc+u)*HH + sx1];
                }
                #pragma unroll
                for (int u = 0; u < 8; u++) {
                    float vv = vsh[cc+u];
                    a0 = fmaf(q0[u], vv, a0); a1 = fmaf(q1[u], vv, a1);
                }
            }
        }
        int p = pbase + w*128 + 2*lane;
        float2 o; o.x = a0; o.y = a1;
        *(float2*)(partial + (size_t)t*NPIX + p) = o;
    }
}

// ---------------- k_fin: logits+sigmoid+bsums -> grid barrier -> stats+blur+tv ----------------
__global__ __launch_bounds__(256) void k_fin(
    const float* __restrict__ partial, const float* __restrict__ biasp,
    const float* __restrict__ alb, const int* __restrict__ choice,
    float* __restrict__ bsums, int* __restrict__ bcnts,
    unsigned* __restrict__ cnt, float* __restrict__ out)
{
    __shared__ float ssum[20]; __shared__ int scnt[20]; __shared__ float sbias;
    __shared__ float av[20];  __shared__ float regsh[20];
    __shared__ float red[256];
    int tid = threadIdx.x;
    if (tid < 20) { ssum[tid] = 0.0f; scnt[tid] = 0; }
    if (tid == 0) {
        float s = alb[0];
        for (int t = 0; t < 18; t++) s += biasp[t];
        sbias = s;
    }
    __syncthreads();
    int p = blockIdx.x*256 + tid;
    float lg = sbias;
    #pragma unroll
    for (int s = 0; s < 18; s++) lg += partial[(size_t)s*NPIX + p];
    float e = 1.0f / (1.0f + expf(-lg));
    int ch = choice[p];
    atomicAdd(&ssum[ch], e);
    atomicAdd(&scnt[ch], 1);
    __syncthreads();
    if (tid < 20) { bsums[blockIdx.x*20 + tid] = ssum[tid]; bcnts[blockIdx.x*20 + tid] = scnt[tid]; }

    gridbar(&cnt[3], 128u);

    if (tid < 20) {
        float s = 0.0f; int c = 0;
        for (int blk = 0; blk < 128; blk++) { s += bsums[blk*20 + tid]; c += bcnts[blk*20 + tid]; }
        float mean = s / fmaxf((float)c, 1.0f);
        av[tid] = (c > 0) ? mean : 1.0f;
        regsh[tid] = (c > 0) ? fmaxf(mean - 0.8f, 0.0f) : 0.0f;
    }
    __syncthreads();
    if (blockIdx.x == 0 && tid == 0) {
        float rs = 0.0f;
        for (int j = 0; j < 20; j++) rs += regsh[j];
        out[OUT_REG] = rs * 0.5f;
    }
    int b = p >> 14, rem = p & 16383, y = rem >> 7, x = rem & 127;
    float k1[5]; float ks = 0.0f;
    #pragma unroll
    for (int i = 0; i < 5; i++) { float d = (float)(i-2) / 1.1f; k1[i] = expf(-0.5f*d*d); ks += k1[i]; }
    #pragma unroll
    for (int i = 0; i < 5; i++) k1[i] /= ks;
    const int* cb = choice + b*16384;
    float acc = 0.0f;
    #pragma unroll
    for (int a = 0; a < 5; a++) {
        int yy = y + a - 2; yy = (yy < 0) ? -yy : ((yy > 127) ? 254 - yy : yy);
        #pragma unroll
        for (int bb = 0; bb < 5; bb++) {
            int xx = x + bb - 2; xx = (xx < 0) ? -xx : ((xx > 127) ? 254 - xx : xx);
            float am = av[cb[yy*128 + xx]];
            float fin = (am < 0.8f) ? 0.0f : am;
            acc += k1[a]*k1[bb]*fin;
        }
    }
    out[OUT_BLUR + p] = acc;
    float amc = av[cb[y*128 + x]];
    float d = e - amc;
    red[tid] = d*d; __syncthreads();
    for (int s = 128; s; s >>= 1) { if (tid < s) red[tid] += red[tid+s]; __syncthreads(); }
    if (tid == 0) atomicAdd(&out[OUT_TV], red[0] * (1.0f/32768.0f));
}

// ---------------- host ----------------
extern "C" void kernel_launch(void* const* d_in, const int* in_sizes, int n_in,
                              void* d_out, int out_size, void* d_ws, size_t ws_size,
                              hipStream_t stream)
{
    const float* x      = (const float*)d_in[0];
    const float* blend  = (const float*)d_in[11];   // fmap_10
    const float* mw     = (const float*)d_in[27];
    const float* mb     = (const float*)d_in[28];
    const float* afw    = (const float*)d_in[29];
    const float* afb    = (const float*)d_in[30];
    const float* aw     = (const float*)d_in[31];
    const float* ab     = (const float*)d_in[32];
    const float* alw    = (const float*)d_in[33];
    const float* alb    = (const float*)d_in[34];
    const float* istate = (const float*)d_in[35];
    float* out = (float*)d_out;
    float* ws  = (float*)d_ws;

    static const int LN[17] = {0,2,3,5,6,8,9,11,12,14,15,17,18,20,21,23,24};
    FPtrs fp;
    fp.f[0] = (const float*)d_in[26];               // fmap_25
    for (int c = 0; c < 17; c++) fp.f[1+c] = (const float*)d_in[1 + LN[c]];

    float* hA     = ws + WS_HA;
    float* hB     = ws + WS_HB;
    float* st     = ws + WS_ST;
    float* cn     = ws + WS_CN;
    float* biasp  = ws + WS_BIASP;
    float* v      = ws + WS_V;
    int*   choice = (int*)(ws + WS_CHOICE);
    float* part   = ws + WS_PART;
    float* bsums  = ws + WS_SUMS;
    int*   bcnts  = (int*)(ws + WS_CNTS);
    unsigned* cntr = (unsigned*)(ws + WS_CNTR);

    k_pre<<<33, 512, 0, stream>>>(afw, afb, aw, ab, alw, istate, v, biasp, st, cn, x, hA, cntr, out);
    k_map<<<896, 256, 0, stream>>>(mw, mb, hA, hB, cntr, out);
    k_mega<<<2368, 256, 0, stream>>>(fp, v, blend, st, cn, choice, part);
    k_fin<<<128, 256, 0, stream>>>(part, biasp, alb, choice, bsums, bcnts, cntr, out);
}

// Round 12
// 138.058 us; speedup vs baseline: 5.5350x; 5.5350x over previous
//
#include <hip/hip_runtime.h>
#include <math.h>

// ---------------- constants ----------------
#define NPIX 32768            // 2 * 128 * 128
#define OUT_DZ 0
#define OUT_BLUR 18432
#define OUT_LD 51200
#define OUT_REG 51201
#define OUT_TV 51202

__constant__ int d_cin[18] = {512,512,512,512,512,512,512,512,256,256,128,128,64,64,32,32,16,16};
__constant__ int d_H[18]   = {4,  4,  8,  16, 32, 32, 64, 128,256,256,256,256,256,256,256,256,256,256};

struct FPtrs { const float* f[18]; };

// ws layout (float offsets)
#define WS_HA     0        // 7168
#define WS_HB     7168     // 7168
#define WS_ST     14336    // 8192
#define WS_CN     22528    // 48
#define WS_BIASP  22576    // 18 (pad to 22656)
#define WS_V      22656    // 9216
#define WS_CHOICE 31872    // 32768 ints
#define WS_PART   64640    // 18*32768 = 589824
#define WS_EACH   654464   // 32768
#define WS_SUMS   687232   // 128*20
#define WS_CNTS   689792   // 128*20 ints

#define WAITVM(N) asm volatile("s_waitcnt vmcnt(" #N ")" ::: "memory")

// ---------------- k_pre: vfold (19 blocks) + RMS norm (14 blocks) ----------------
__global__ __launch_bounds__(512) void k_pre(
    const float* __restrict__ afw, const float* __restrict__ afb,
    const float* __restrict__ aw,  const float* __restrict__ ab,
    const float* __restrict__ alw, const float* __restrict__ istate,
    float* __restrict__ v, float* __restrict__ biasp,
    float* __restrict__ st, float* __restrict__ cn,
    const float* __restrict__ x, float* __restrict__ h, float* __restrict__ out)
{
    __shared__ float red[512];
    __shared__ float scale;
    int bid = blockIdx.x;
    int tid = threadIdx.x;
    if (bid == 19 && tid == 0) out[OUT_TV] = 0.0f;   // zero tv accumulator each call
    if (bid < 18) {
        int t = bid;
        int cin = d_cin[t];
        const float* w  = (t==0) ? afw : aw + (size_t)(t-1)*32*512;
        const float* bb = (t==0) ? afb : ab + (t-1)*32;
        float sc = (1.0f/sqrtf((float)cin)) * (1.0f/24.0f);
        if (tid < cin) {
            float s = 0.0f;
            #pragma unroll 8
            for (int o = 0; o < 32; o++) s += alw[t*32+o] * w[o*512 + tid];
            v[t*512 + tid] = s * sc;
        }
        if (tid == 0) {
            float s = 0.0f;
            for (int o = 0; o < 32; o++) s += alw[t*32+o] * bb[o];
            biasp[t] = s * (1.0f/24.0f);
        }
    } else if (bid == 18) {
        if (tid < 512) {
            #pragma unroll
            for (int j = 0; j < 10; j++) st[tid*16 + j] = -2.0f * istate[j*576 + tid];
        }
        if (tid < 10) {
            int j = tid;
            float n = 0.0f, s1 = 0.0f, s2 = 0.0f;
            for (int k = 0; k < 576; k++) { float sv = istate[j*576+k]; n += sv*sv; }
            for (int k = 512; k < 544; k++) s1 += istate[j*576+k];
            for (int k = 544; k < 576; k++) s2 += istate[j*576+k];
            cn[j] = n; cn[16+j] = -2.0f*s1; cn[32+j] = -2.0f*s2;
        }
    } else {
        int r = bid - 19;             // 0..13 (b*7+c)
        int b = r / 7, c = r % 7;
        const float* xr = x + ((size_t)b*18 + c)*512;
        float v0 = xr[tid];
        red[tid] = v0*v0; __syncthreads();
        for (int s = 256; s; s >>= 1) { if (tid < s) red[tid] += red[tid+s]; __syncthreads(); }
        if (tid == 0) scale = 1.0f / sqrtf(red[0]*(1.0f/512.0f) + 1e-8f);
        __syncthreads();
        h[r*512 + tid] = v0*scale;
    }
}

// ---------------- mapper: one MLP layer ----------------
__global__ __launch_bounds__(256) void k_mlp(
    const float* __restrict__ mw, const float* __restrict__ mb,
    const float* __restrict__ hin, float* __restrict__ hout,
    int layer, float* __restrict__ dz)
{
    int wave = blockIdx.x*4 + (threadIdx.x >> 6);
    int lane = threadIdx.x & 63;
    int c = wave >> 9, o = wave & 511;
    const float* wrow = mw + (((size_t)(c*3 + layer)*512 + o) << 9) + lane*8;
    float4 w0 = *(const float4*)wrow;
    float4 w1 = *(const float4*)(wrow + 4);
    const float* h0 = hin + (size_t)c*512 + lane*8;
    const float* h1 = hin + (size_t)(7 + c)*512 + lane*8;
    float4 a0 = *(const float4*)h0, a1 = *(const float4*)(h0+4);
    float4 b0 = *(const float4*)h1, b1 = *(const float4*)(h1+4);
    float d0 = a0.x*w0.x + a0.y*w0.y + a0.z*w0.z + a0.w*w0.w
             + a1.x*w1.x + a1.y*w1.y + a1.z*w1.z + a1.w*w1.w;
    float d1 = b0.x*w0.x + b0.y*w0.y + b0.z*w0.z + b0.w*w0.w
             + b1.x*w1.x + b1.y*w1.y + b1.z*w1.z + b1.w*w1.w;
    #pragma unroll
    for (int m = 32; m; m >>= 1) { d0 += __shfl_xor(d0, m); d1 += __shfl_xor(d1, m); }
    if (lane == 0) {
        const float wsc = (float)(0.1/22.62741699796952);
        const float rt2 = 1.41421356237309515f;
        float bias = mb[(c*3 + layer)*512 + o] * 0.1f;
        float z0 = d0*wsc + bias; z0 = (z0 > 0.0f ? z0 : 0.2f*z0) * rt2;
        float z1 = d1*wsc + bias; z1 = (z1 > 0.0f ? z1 : 0.2f*z1) * rt2;
        hout[(size_t)c*512 + o] = z0;
        hout[(size_t)(7 + c)*512 + o] = z1;
        if (dz) {
            dz[((size_t)0*18 + c)*512 + o] = z0;
            dz[((size_t)1*18 + c)*512 + o] = z1;
        }
    }
}

// ---------------- MEGA: heavy(1408) + assign-stream(128) + light(448) + zero(44) + lossdelta(1) ----------------
// macro-tile of 31 blocks = 22 heavy + 2 assign + 7 light; 64 macro-tiles = 1984.
__global__ __launch_bounds__(256) void k_mega(FPtrs fp, const float* __restrict__ v,
    const float* __restrict__ blend, const float* __restrict__ st,
    const float* __restrict__ cn, int* __restrict__ choice,
    float* __restrict__ partial, const float* __restrict__ hB, float* __restrict__ out)
{
    __shared__ float smem[16896];   // 67584 B
    int bid = blockIdx.x;
    int tid = threadIdx.x;

    if (bid < 1984) {
        int mk = bid / 31, mr = bid % 31;
        if (mr < 22) {
            // ================= HEAVY (R8-validated counted-vmcnt pipeline) =================
            int hid = mk*22 + mr;
            float (*buf)[4096] = (float(*)[4096])smem;
            float* vsh = smem + 16384;
            int t, b, rblk;
            if (hid < 128) { t = 7; b = hid >> 6; rblk = hid & 63; }
            else { int idx = hid - 128; t = 8 + (idx >> 7); int sub = idx & 127; b = sub >> 6; rblk = sub & 63; }
            int ch = d_cin[t];
            int H  = d_H[t];
            int y0 = rblk*2;
            int w = tid >> 6, lane = tid & 63;
            const float* base = fp.f[t] + (size_t)b*ch*(size_t)H*H;
            for (int i = tid; i < ch; i += 256) vsh[i] = v[t*512 + i];
            __syncthreads();

            int NP = (H == 128) ? (ch >> 4) : (ch >> 3);
            int S = (NP < 3) ? NP : 3;
            for (int q = 0; q < S; q++) {
                if (H == 256) {
                    #pragma unroll
                    for (int k = 0; k < 2; k++) {
                        int cl = 2*w + k;
                        const float* srcc = base + (size_t)(q*8 + cl)*65536 + (size_t)(2*y0)*256 + lane*4;
                        __builtin_amdgcn_global_load_lds(srcc,       &buf[q][(cl*2    )*256], 16, 0, 0);
                        __builtin_amdgcn_global_load_lds(srcc + 512, &buf[q][(cl*2 + 1)*256], 16, 0, 0);
                    }
                } else {
                    #pragma unroll
                    for (int k = 0; k < 4; k++) {
                        int cl = 4*w + k;
                        const float* srcc = base + (size_t)(q*16 + cl)*16384 + (size_t)y0*128 + lane*4;
                        __builtin_amdgcn_global_load_lds(srcc, &buf[q][cl*256], 16, 0, 0);
                    }
                }
            }
            int r = tid >> 7, x = tid & 127;
            float acc = 0.0f;
            for (int p = 0; p < NP; p++) {
                int ahead = S - p - 1;
                if (ahead >= 2)      { WAITVM(8); }
                else if (ahead == 1) { WAITVM(4); }
                else                 { WAITVM(0); }
                __builtin_amdgcn_sched_barrier(0);
                __builtin_amdgcn_s_barrier();
                __builtin_amdgcn_sched_barrier(0);
                if (S < NP) {
                    int q = S & 3;
                    if (H == 256) {
                        #pragma unroll
                        for (int k = 0; k < 2; k++) {
                            int cl = 2*w + k;
                            const float* srcc = base + (size_t)(S*8 + cl)*65536 + (size_t)(2*y0)*256 + lane*4;
                            __builtin_amdgcn_global_load_lds(srcc,       &buf[q][(cl*2    )*256], 16, 0, 0);
                            __builtin_amdgcn_global_load_lds(srcc + 512, &buf[q][(cl*2 + 1)*256], 16, 0, 0);
                        }
                    } else {
                        #pragma unroll
                        for (int k = 0; k < 4; k++) {
                            int cl = 4*w + k;
                            const float* srcc = base + (size_t)(S*16 + cl)*16384 + (size_t)y0*128 + lane*4;
                            __builtin_amdgcn_global_load_lds(srcc, &buf[q][cl*256], 16, 0, 0);
                        }
                    }
                    S++;
                }
                __builtin_amdgcn_sched_barrier(0);
                const float* bp = buf[p & 3];
                if (H == 256) {
                    int cb = p*8;
                    #pragma unroll
                    for (int cp = 0; cp < 8; cp++)
                        acc = fmaf(bp[(cp*2 + r)*256 + 2*x], vsh[cb + cp], acc);
                } else {
                    int cb = p*16;
                    #pragma unroll
                    for (int cp = 0; cp < 16; cp++)
                        acc = fmaf(bp[cp*256 + r*128 + x], vsh[cb + cp], acc);
                }
            }
            partial[(size_t)t*NPIX + b*16384 + (size_t)(y0 + r)*128 + x] = acc;
        } else if (mr < 24) {
            // ================= ASSIGN (streaming, heavy-style pipeline) =================
            // block = 2 rows x 128 cols of one batch; 8 channels/phase (1KB/ch), 4-deep ring.
            int aid = mk*2 + (mr - 22);          // 0..127
            float (*buf)[2048] = (float(*)[2048])smem;   // 4 x 8KB
            float* stsh = smem + 8192;                    // [512][10] compact = 5120 floats
            int b  = aid >> 6;
            int y0 = (aid & 63)*2;
            int w = tid >> 6, lane = tid & 63;
            const float* base = blend + (size_t)b*512*16384 + (size_t)y0*128;
            for (int i = tid; i < 5120; i += 256) {
                int c = i / 10, j = i - c*10;
                stsh[i] = st[c*16 + j];
            }
            __syncthreads();
            const int NP = 64;                   // 512 / 8
            int S = 3;
            for (int q = 0; q < S; q++) {
                #pragma unroll
                for (int k = 0; k < 2; k++) {
                    int cl = 2*w + k;
                    const float* srcc = base + (size_t)(q*8 + cl)*16384 + lane*4;
                    __builtin_amdgcn_global_load_lds(srcc, &buf[q][cl*256], 16, 0, 0);
                }
            }
            float g[10] = {0,0,0,0,0,0,0,0,0,0};
            for (int p = 0; p < NP; p++) {
                int ahead = S - p - 1;
                if (ahead >= 2)      { WAITVM(4); }
                else if (ahead == 1) { WAITVM(2); }
                else                 { WAITVM(0); }
                __builtin_amdgcn_sched_barrier(0);
                __builtin_amdgcn_s_barrier();
                __builtin_amdgcn_sched_barrier(0);
                if (S < NP) {
                    int q = S & 3;
                    #pragma unroll
                    for (int k = 0; k < 2; k++) {
                        int cl = 2*w + k;
                        const float* srcc = base + (size_t)(S*8 + cl)*16384 + lane*4;
                        __builtin_amdgcn_global_load_lds(srcc, &buf[q][cl*256], 16, 0, 0);
                    }
                    S++;
                }
                __builtin_amdgcn_sched_barrier(0);
                const float* bp = buf[p & 3];
                int cb = p*8;
                #pragma unroll
                for (int cl = 0; cl < 8; cl++) {
                    float q = bp[cl*256 + tid];
                    const float* sr = &stsh[(cb + cl)*10];
                    #pragma unroll
                    for (int j = 0; j < 10; j++) g[j] = fmaf(q, sr[j], g[j]);
                }
            }
            int r = tid >> 7, x = tid & 127;
            int y = y0 + r;
            float cx = (float)x * (float)(2.0/127.0) - 1.0f;
            float cy = (float)y * (float)(2.0/127.0) - 1.0f;
            int best = 0;
            float bg = g[0] + cn[0] + cn[16]*cx + cn[32]*cy;
            #pragma unroll
            for (int j = 1; j < 10; j++) {
                float gt = g[j] + cn[j] + cn[16+j]*cx + cn[32+j]*cy;
                if (gt < bg) { bg = gt; best = j; }
            }
            choice[aid*256 + tid] = b*10 + best;
        } else {
            // ================= LIGHT (validated gather) =================
            int lid = mk*7 + (mr - 24);
            float* vsh = smem;
            int t  = lid >> 6;
            int nc = d_cin[t];
            int H  = d_H[t];
            for (int i = tid; i < nc; i += 256) vsh[i] = v[t*512 + i];
            __syncthreads();
            int w = tid >> 6, lane = tid & 63;
            int px = lid & 63;
            int pbase = px*512;
            int b = pbase >> 14;
            int y = ((pbase & 16383) >> 7) + w;
            const float* base = fp.f[t] + (size_t)b*nc*(size_t)(H*H);
            float a0 = 0.0f, a1 = 0.0f;
            if (H == 64) {
                const float* src = base + (size_t)(y >> 1)*64 + lane;
                for (int cc = 0; cc < nc; cc += 8) {
                    float q[8];
                    #pragma unroll
                    for (int u = 0; u < 8; u++) q[u] = src[(size_t)(cc+u)*4096];
                    #pragma unroll
                    for (int u = 0; u < 8; u++) {
                        float vv = vsh[cc+u];
                        a0 = fmaf(q[u], vv, a0); a1 = fmaf(q[u], vv, a1);
                    }
                }
            } else {
                int x0 = 2*lane, x1 = 2*lane + 1;
                int sy = (y*H) >> 7, sx0 = (x0*H) >> 7, sx1 = (x1*H) >> 7;
                const float* src = base + (size_t)sy*H;
                size_t HH = (size_t)H*H;
                for (int cc = 0; cc < nc; cc += 8) {
                    float q0[8], q1[8];
                    #pragma unroll
                    for (int u = 0; u < 8; u++) {
                        q0[u] = src[(size_t)(cc+u)*HH + sx0];
                        q1[u] = src[(size_t)(cc+u)*HH + sx1];
                    }
                    #pragma unroll
                    for (int u = 0; u < 8; u++) {
                        float vv = vsh[cc+u];
                        a0 = fmaf(q0[u], vv, a0); a1 = fmaf(q1[u], vv, a1);
                    }
                }
            }
            int p = pbase + w*128 + 2*lane;
            float2 o; o.x = a0; o.y = a1;
            *(float2*)(partial + (size_t)t*NPIX + p) = o;
        }
    } else if (bid < 2028) {
        // ================= ZERO tail of delta_zs =================
        int z = (bid - 1984)*256 + tid;
        if (z < 11264) {
            int b = z / (11*512), rem = z % (11*512);
            out[(size_t)b*18*512 + 7*512 + rem] = 0.0f;
        }
    } else {
        // ================= LOSS_DELTA (1 block) =================
        float total = 0.0f;
        for (int r = 0; r < 14; r++) {
            float v0 = hB[r*512 + tid], v1 = hB[r*512 + 256 + tid];
            smem[tid] = v0*v0 + v1*v1; __syncthreads();
            for (int s = 128; s; s >>= 1) { if (tid < s) smem[tid] += smem[tid+s]; __syncthreads(); }
            if (tid == 0) total += sqrtf(smem[0]);
            __syncthreads();
        }
        if (tid == 0) out[OUT_LD] = total * (1.0f/14.0f);
    }
}

// ---------------- logits -> sigmoid -> segment partials ----------------
__global__ __launch_bounds__(256) void k_logits(
    const float* __restrict__ partial, const float* __restrict__ biasp,
    const float* __restrict__ alb, const int* __restrict__ choice,
    float* __restrict__ each, float* __restrict__ bsums, int* __restrict__ bcnts)
{
    __shared__ float ssum[20]; __shared__ int scnt[20]; __shared__ float sbias;
    int tid = threadIdx.x;
    if (tid < 20) { ssum[tid] = 0.0f; scnt[tid] = 0; }
    if (tid == 0) {
        float s = alb[0];
        for (int t = 0; t < 18; t++) s += biasp[t];
        sbias = s;
    }
    __syncthreads();
    int p = blockIdx.x*256 + tid;
    float lg = sbias;
    #pragma unroll
    for (int s = 0; s < 18; s++) lg += partial[(size_t)s*NPIX + p];
    float e = 1.0f / (1.0f + expf(-lg));
    each[p] = e;
    int ch = choice[p];
    atomicAdd(&ssum[ch], e);
    atomicAdd(&scnt[ch], 1);
    __syncthreads();
    if (tid < 20) { bsums[blockIdx.x*20 + tid] = ssum[tid]; bcnts[blockIdx.x*20 + tid] = scnt[tid]; }
}

// ---------------- final: stats (inline, redundant per block) + blur + loss_tv ----------------
__global__ __launch_bounds__(256) void k_final(
    const float* __restrict__ each, const int* __restrict__ choice,
    const float* __restrict__ bsums, const int* __restrict__ bcnts,
    float* __restrict__ out)
{
    __shared__ float av[20];
    __shared__ float regsh[20];
    __shared__ float red[256];
    int tid = threadIdx.x;
    if (tid < 20) {
        float s = 0.0f; int c = 0;
        for (int blk = 0; blk < 128; blk++) { s += bsums[blk*20 + tid]; c += bcnts[blk*20 + tid]; }
        float mean = s / fmaxf((float)c, 1.0f);
        av[tid] = (c > 0) ? mean : 1.0f;
        regsh[tid] = (c > 0) ? fmaxf(mean - 0.8f, 0.0f) : 0.0f;
    }
    __syncthreads();
    if (blockIdx.x == 0 && tid == 0) {
        float rs = 0.0f;
        for (int j = 0; j < 20; j++) rs += regsh[j];
        out[OUT_REG] = rs * 0.5f;
    }
    int p = blockIdx.x*256 + tid;
    int b = p >> 14, rem = p & 16383, y = rem >> 7, x = rem & 127;
    float k1[5]; float ks = 0.0f;
    #pragma unroll
    for (int i = 0; i < 5; i++) { float d = (float)(i-2) / 1.1f; k1[i] = expf(-0.5f*d*d); ks += k1[i]; }
    #pragma unroll
    for (int i = 0; i < 5; i++) k1[i] /= ks;
    const int* cb = choice + b*16384;
    float acc = 0.0f;
    #pragma unroll
    for (int a = 0; a < 5; a++) {
        int yy = y + a - 2; yy = (yy < 0) ? -yy : ((yy > 127) ? 254 - yy : yy);
        #pragma unroll
        for (int bb = 0; bb < 5; bb++) {
            int xx = x + bb - 2; xx = (xx < 0) ? -xx : ((xx > 127) ? 254 - xx : xx);
            float am = av[cb[yy*128 + xx]];
            float fin = (am < 0.8f) ? 0.0f : am;
            acc += k1[a]*k1[bb]*fin;
        }
    }
    out[OUT_BLUR + p] = acc;
    float amc = av[cb[y*128 + x]];
    float d = each[p] - amc;
    red[tid] = d*d; __syncthreads();
    for (int s = 128; s; s >>= 1) { if (tid < s) red[tid] += red[tid+s]; __syncthreads(); }
    if (tid == 0) atomicAdd(&out[OUT_TV], red[0] * (1.0f/32768.0f));
}

// ---------------- host ----------------
extern "C" void kernel_launch(void* const* d_in, const int* in_sizes, int n_in,
                              void* d_out, int out_size, void* d_ws, size_t ws_size,
                              hipStream_t stream)
{
    const float* x      = (const float*)d_in[0];
    const float* blend  = (const float*)d_in[11];   // fmap_10
    const float* mw     = (const float*)d_in[27];
    const float* mb     = (const float*)d_in[28];
    const float* afw    = (const float*)d_in[29];
    const float* afb    = (const float*)d_in[30];
    const float* aw     = (const float*)d_in[31];
    const float* ab     = (const float*)d_in[32];
    const float* alw    = (const float*)d_in[33];
    const float* alb    = (const float*)d_in[34];
    const float* istate = (const float*)d_in[35];
    float* out = (float*)d_out;
    float* ws  = (float*)d_ws;

    static const int LN[17] = {0,2,3,5,6,8,9,11,12,14,15,17,18,20,21,23,24};
    FPtrs fp;
    fp.f[0] = (const float*)d_in[26];               // fmap_25
    for (int c = 0; c < 17; c++) fp.f[1+c] = (const float*)d_in[1 + LN[c]];

    float* hA     = ws + WS_HA;
    float* hB     = ws + WS_HB;
    float* st     = ws + WS_ST;
    float* cn     = ws + WS_CN;
    float* biasp  = ws + WS_BIASP;
    float* v      = ws + WS_V;
    int*   choice = (int*)(ws + WS_CHOICE);
    float* part   = ws + WS_PART;
    float* each   = ws + WS_EACH;
    float* bsums  = ws + WS_SUMS;
    int*   bcnts  = (int*)(ws + WS_CNTS);

    k_pre<<<33, 512, 0, stream>>>(afw, afb, aw, ab, alw, istate, v, biasp, st, cn, x, hA, out);
    k_mlp<<<896, 256, 0, stream>>>(mw, mb, hA, hB, 0, nullptr);
    k_mlp<<<896, 256, 0, stream>>>(mw, mb, hB, hA, 1, nullptr);
    k_mlp<<<896, 256, 0, stream>>>(mw, mb, hA, hB, 2, out + OUT_DZ);
    k_mega<<<2029, 256, 0, stream>>>(fp, v, blend, st, cn, choice, part, hB, out);
    k_logits<<<128, 256, 0, stream>>>(part, biasp, alb, choice, each, bsums, bcnts);
    k_final<<<128, 256, 0, stream>>>(each, choice, bsums, bcnts, out);
}

// Round 13
// 133.979 us; speedup vs baseline: 5.7035x; 1.0304x over previous
//
#include <hip/hip_runtime.h>
#include <math.h>

// ---------------- constants ----------------
#define NPIX 32768            // 2 * 128 * 128
#define OUT_DZ 0
#define OUT_BLUR 18432
#define OUT_LD 51200
#define OUT_REG 51201
#define OUT_TV 51202

__constant__ int d_cin[18] = {512,512,512,512,512,512,512,512,256,256,128,128,64,64,32,32,16,16};
__constant__ int d_H[18]   = {4,  4,  8,  16, 32, 32, 64, 128,256,256,256,256,256,256,256,256,256,256};

struct FPtrs { const float* f[18]; };

// ws layout (float offsets)
#define WS_HA     0        // 7168
#define WS_HB     7168     // 7168
#define WS_ST     14336    // 8192
#define WS_CN     22528    // 48
#define WS_BIASP  22576    // 18 (pad to 22656)
#define WS_V      22656    // 9216
#define WS_CHOICE 31872    // 32768 ints
#define WS_PART   64640    // 18*32768 = 589824
#define WS_EACH   654464   // 32768
#define WS_SUMS   687232   // 128*20
#define WS_CNTS   689792   // 128*20 ints

#define WAITVM(N) asm volatile("s_waitcnt vmcnt(" #N ")" ::: "memory")

// ---------------- k_pre: vfold (19 blocks) + RMS norm (14 blocks) ----------------
__global__ __launch_bounds__(512) void k_pre(
    const float* __restrict__ afw, const float* __restrict__ afb,
    const float* __restrict__ aw,  const float* __restrict__ ab,
    const float* __restrict__ alw, const float* __restrict__ istate,
    float* __restrict__ v, float* __restrict__ biasp,
    float* __restrict__ st, float* __restrict__ cn,
    const float* __restrict__ x, float* __restrict__ h, float* __restrict__ out)
{
    __shared__ float red[512];
    __shared__ float scale;
    int bid = blockIdx.x;
    int tid = threadIdx.x;
    if (bid == 19 && tid == 0) out[OUT_TV] = 0.0f;   // zero tv accumulator each call
    if (bid < 18) {
        int t = bid;
        int cin = d_cin[t];
        const float* w  = (t==0) ? afw : aw + (size_t)(t-1)*32*512;
        const float* bb = (t==0) ? afb : ab + (t-1)*32;
        float sc = (1.0f/sqrtf((float)cin)) * (1.0f/24.0f);
        if (tid < cin) {
            float s = 0.0f;
            #pragma unroll 8
            for (int o = 0; o < 32; o++) s += alw[t*32+o] * w[o*512 + tid];
            v[t*512 + tid] = s * sc;
        }
        if (tid == 0) {
            float s = 0.0f;
            for (int o = 0; o < 32; o++) s += alw[t*32+o] * bb[o];
            biasp[t] = s * (1.0f/24.0f);
        }
    } else if (bid == 18) {
        if (tid < 512) {
            #pragma unroll
            for (int j = 0; j < 10; j++) st[tid*16 + j] = -2.0f * istate[j*576 + tid];
        }
        if (tid < 10) {
            int j = tid;
            float n = 0.0f, s1 = 0.0f, s2 = 0.0f;
            for (int k = 0; k < 576; k++) { float sv = istate[j*576+k]; n += sv*sv; }
            for (int k = 512; k < 544; k++) s1 += istate[j*576+k];
            for (int k = 544; k < 576; k++) s2 += istate[j*576+k];
            cn[j] = n; cn[16+j] = -2.0f*s1; cn[32+j] = -2.0f*s2;
        }
    } else {
        int r = bid - 19;             // 0..13 (b*7+c)
        int b = r / 7, c = r % 7;
        const float* xr = x + ((size_t)b*18 + c)*512;
        float v0 = xr[tid];
        red[tid] = v0*v0; __syncthreads();
        for (int s = 256; s; s >>= 1) { if (tid < s) red[tid] += red[tid+s]; __syncthreads(); }
        if (tid == 0) scale = 1.0f / sqrtf(red[0]*(1.0f/512.0f) + 1e-8f);
        __syncthreads();
        h[r*512 + tid] = v0*scale;
    }
}

// ---------------- mapper: one MLP layer ----------------
__global__ __launch_bounds__(256) void k_mlp(
    const float* __restrict__ mw, const float* __restrict__ mb,
    const float* __restrict__ hin, float* __restrict__ hout,
    int layer, float* __restrict__ dz)
{
    int wave = blockIdx.x*4 + (threadIdx.x >> 6);
    int lane = threadIdx.x & 63;
    int c = wave >> 9, o = wave & 511;
    const float* wrow = mw + (((size_t)(c*3 + layer)*512 + o) << 9) + lane*8;
    float4 w0 = *(const float4*)wrow;
    float4 w1 = *(const float4*)(wrow + 4);
    const float* h0 = hin + (size_t)c*512 + lane*8;
    const float* h1 = hin + (size_t)(7 + c)*512 + lane*8;
    float4 a0 = *(const float4*)h0, a1 = *(const float4*)(h0+4);
    float4 b0 = *(const float4*)h1, b1 = *(const float4*)(h1+4);
    float d0 = a0.x*w0.x + a0.y*w0.y + a0.z*w0.z + a0.w*w0.w
             + a1.x*w1.x + a1.y*w1.y + a1.z*w1.z + a1.w*w1.w;
    float d1 = b0.x*w0.x + b0.y*w0.y + b0.z*w0.z + b0.w*w0.w
             + b1.x*w1.x + b1.y*w1.y + b1.z*w1.z + b1.w*w1.w;
    #pragma unroll
    for (int m = 32; m; m >>= 1) { d0 += __shfl_xor(d0, m); d1 += __shfl_xor(d1, m); }
    if (lane == 0) {
        const float wsc = (float)(0.1/22.62741699796952);
        const float rt2 = 1.41421356237309515f;
        float bias = mb[(c*3 + layer)*512 + o] * 0.1f;
        float z0 = d0*wsc + bias; z0 = (z0 > 0.0f ? z0 : 0.2f*z0) * rt2;
        float z1 = d1*wsc + bias; z1 = (z1 > 0.0f ? z1 : 0.2f*z1) * rt2;
        hout[(size_t)c*512 + o] = z0;
        hout[(size_t)(7 + c)*512 + o] = z1;
        if (dz) {
            dz[((size_t)0*18 + c)*512 + o] = z0;
            dz[((size_t)1*18 + c)*512 + o] = z1;
        }
    }
}

// ---------------- MEGA: heavy(1408) + assign-stream(128) + light(448) + zero(44) + lossdelta(1) ----------------
// macro-tile of 31 blocks = 22 heavy + 2 assign + 7 light; 64 macro-tiles = 1984.
// LDS trimmed to 51200 B (ring-3) -> 3 blocks/CU.
__global__ __launch_bounds__(256) void k_mega(FPtrs fp, const float* __restrict__ v,
    const float* __restrict__ blend, const float* __restrict__ st,
    const float* __restrict__ cn, int* __restrict__ choice,
    float* __restrict__ partial, const float* __restrict__ hB, float* __restrict__ out)
{
    __shared__ float smem[12800];   // 51200 B
    int bid = blockIdx.x;
    int tid = threadIdx.x;

    if (bid < 1984) {
        int mk = bid / 31, mr = bid % 31;
        if (mr < 22) {
            // ================= HEAVY (counted-vmcnt pipeline, ring-3) =================
            int hid = mk*22 + mr;
            float (*buf)[4096] = (float(*)[4096])smem;   // 3 x 16 KB
            float* vsh = smem + 12288;
            int t, b, rblk;
            if (hid < 128) { t = 7; b = hid >> 6; rblk = hid & 63; }
            else { int idx = hid - 128; t = 8 + (idx >> 7); int sub = idx & 127; b = sub >> 6; rblk = sub & 63; }
            int ch = d_cin[t];
            int H  = d_H[t];
            int y0 = rblk*2;
            int w = tid >> 6, lane = tid & 63;
            const float* base = fp.f[t] + (size_t)b*ch*(size_t)H*H;
            for (int i = tid; i < ch; i += 256) vsh[i] = v[t*512 + i];
            __syncthreads();

            int NP = (H == 128) ? (ch >> 4) : (ch >> 3);
            int S = (NP < 2) ? NP : 2;
            for (int q = 0; q < S; q++) {
                if (H == 256) {
                    #pragma unroll
                    for (int k = 0; k < 2; k++) {
                        int cl = 2*w + k;
                        const float* srcc = base + (size_t)(q*8 + cl)*65536 + (size_t)(2*y0)*256 + lane*4;
                        __builtin_amdgcn_global_load_lds(srcc,       &buf[q][(cl*2    )*256], 16, 0, 0);
                        __builtin_amdgcn_global_load_lds(srcc + 512, &buf[q][(cl*2 + 1)*256], 16, 0, 0);
                    }
                } else {
                    #pragma unroll
                    for (int k = 0; k < 4; k++) {
                        int cl = 4*w + k;
                        const float* srcc = base + (size_t)(q*16 + cl)*16384 + (size_t)y0*128 + lane*4;
                        __builtin_amdgcn_global_load_lds(srcc, &buf[q][cl*256], 16, 0, 0);
                    }
                }
            }
            int r = tid >> 7, x = tid & 127;
            float acc = 0.0f;
            for (int p = 0; p < NP; p++) {
                if (S - p - 1 >= 1) { WAITVM(4); }
                else                { WAITVM(0); }
                __builtin_amdgcn_sched_barrier(0);
                __builtin_amdgcn_s_barrier();
                __builtin_amdgcn_sched_barrier(0);
                if (S < NP) {                    // stage phase S into buf[S%3]
                    int q = S - (S/3)*3;
                    if (H == 256) {
                        #pragma unroll
                        for (int k = 0; k < 2; k++) {
                            int cl = 2*w + k;
                            const float* srcc = base + (size_t)(S*8 + cl)*65536 + (size_t)(2*y0)*256 + lane*4;
                            __builtin_amdgcn_global_load_lds(srcc,       &buf[q][(cl*2    )*256], 16, 0, 0);
                            __builtin_amdgcn_global_load_lds(srcc + 512, &buf[q][(cl*2 + 1)*256], 16, 0, 0);
                        }
                    } else {
                        #pragma unroll
                        for (int k = 0; k < 4; k++) {
                            int cl = 4*w + k;
                            const float* srcc = base + (size_t)(S*16 + cl)*16384 + (size_t)y0*128 + lane*4;
                            __builtin_amdgcn_global_load_lds(srcc, &buf[q][cl*256], 16, 0, 0);
                        }
                    }
                    S++;
                }
                __builtin_amdgcn_sched_barrier(0);
                const float* bp = buf[p - (p/3)*3];
                if (H == 256) {
                    int cb = p*8;
                    #pragma unroll
                    for (int cp = 0; cp < 8; cp++)
                        acc = fmaf(bp[(cp*2 + r)*256 + 2*x], vsh[cb + cp], acc);
                } else {
                    int cb = p*16;
                    #pragma unroll
                    for (int cp = 0; cp < 16; cp++)
                        acc = fmaf(bp[cp*256 + r*128 + x], vsh[cb + cp], acc);
                }
            }
            partial[(size_t)t*NPIX + b*16384 + (size_t)(y0 + r)*128 + x] = acc;
        } else if (mr < 24) {
            // ================= ASSIGN (streaming pipeline, ring-3) =================
            int aid = mk*2 + (mr - 22);          // 0..127
            float (*buf)[2048] = (float(*)[2048])smem;   // 3 x 8KB
            float* stsh = smem + 6144;                    // [512][10] compact = 5120 floats
            int b  = aid >> 6;
            int y0 = (aid & 63)*2;
            int w = tid >> 6, lane = tid & 63;
            const float* base = blend + (size_t)b*512*16384 + (size_t)y0*128;
            for (int i = tid; i < 5120; i += 256) {
                int c = i / 10, j = i - c*10;
                stsh[i] = st[c*16 + j];
            }
            __syncthreads();
            const int NP = 64;                   // 512 / 8
            int S = 2;
            for (int q = 0; q < S; q++) {
                #pragma unroll
                for (int k = 0; k < 2; k++) {
                    int cl = 2*w + k;
                    const float* srcc = base + (size_t)(q*8 + cl)*16384 + lane*4;
                    __builtin_amdgcn_global_load_lds(srcc, &buf[q][cl*256], 16, 0, 0);
                }
            }
            float g[10] = {0,0,0,0,0,0,0,0,0,0};
            for (int p = 0; p < NP; p++) {
                if (S - p - 1 >= 1) { WAITVM(2); }
                else                { WAITVM(0); }
                __builtin_amdgcn_sched_barrier(0);
                __builtin_amdgcn_s_barrier();
                __builtin_amdgcn_sched_barrier(0);
                if (S < NP) {
                    int q = S - (S/3)*3;
                    #pragma unroll
                    for (int k = 0; k < 2; k++) {
                        int cl = 2*w + k;
                        const float* srcc = base + (size_t)(S*8 + cl)*16384 + lane*4;
                        __builtin_amdgcn_global_load_lds(srcc, &buf[q][cl*256], 16, 0, 0);
                    }
                    S++;
                }
                __builtin_amdgcn_sched_barrier(0);
                const float* bp = buf[p - (p/3)*3];
                int cb = p*8;
                #pragma unroll
                for (int cl = 0; cl < 8; cl++) {
                    float q = bp[cl*256 + tid];
                    const float* sr = &stsh[(cb + cl)*10];
                    #pragma unroll
                    for (int j = 0; j < 10; j++) g[j] = fmaf(q, sr[j], g[j]);
                }
            }
            int r = tid >> 7, x = tid & 127;
            int y = y0 + r;
            float cx = (float)x * (float)(2.0/127.0) - 1.0f;
            float cy = (float)y * (float)(2.0/127.0) - 1.0f;
            int best = 0;
            float bg = g[0] + cn[0] + cn[16]*cx + cn[32]*cy;
            #pragma unroll
            for (int j = 1; j < 10; j++) {
                float gt = g[j] + cn[j] + cn[16+j]*cx + cn[32+j]*cy;
                if (gt < bg) { bg = gt; best = j; }
            }
            choice[aid*256 + tid] = b*10 + best;
        } else {
            // ================= LIGHT (validated gather) =================
            int lid = mk*7 + (mr - 24);
            float* vsh = smem;
            int t  = lid >> 6;
            int nc = d_cin[t];
            int H  = d_H[t];
            for (int i = tid; i < nc; i += 256) vsh[i] = v[t*512 + i];
            __syncthreads();
            int w = tid >> 6, lane = tid & 63;
            int px = lid & 63;
            int pbase = px*512;
            int b = pbase >> 14;
            int y = ((pbase & 16383) >> 7) + w;
            const float* base = fp.f[t] + (size_t)b*nc*(size_t)(H*H);
            float a0 = 0.0f, a1 = 0.0f;
            if (H == 64) {
                const float* src = base + (size_t)(y >> 1)*64 + lane;
                for (int cc = 0; cc < nc; cc += 8) {
                    float q[8];
                    #pragma unroll
                    for (int u = 0; u < 8; u++) q[u] = src[(size_t)(cc+u)*4096];
                    #pragma unroll
                    for (int u = 0; u < 8; u++) {
                        float vv = vsh[cc+u];
                        a0 = fmaf(q[u], vv, a0); a1 = fmaf(q[u], vv, a1);
                    }
                }
            } else {
                int x0 = 2*lane, x1 = 2*lane + 1;
                int sy = (y*H) >> 7, sx0 = (x0*H) >> 7, sx1 = (x1*H) >> 7;
                const float* src = base + (size_t)sy*H;
                size_t HH = (size_t)H*H;
                for (int cc = 0; cc < nc; cc += 8) {
                    float q0[8], q1[8];
                    #pragma unroll
                    for (int u = 0; u < 8; u++) {
                        q0[u] = src[(size_t)(cc+u)*HH + sx0];
                        q1[u] = src[(size_t)(cc+u)*HH + sx1];
                    }
                    #pragma unroll
                    for (int u = 0; u < 8; u++) {
                        float vv = vsh[cc+u];
                        a0 = fmaf(q0[u], vv, a0); a1 = fmaf(q1[u], vv, a1);
                    }
                }
            }
            int p = pbase + w*128 + 2*lane;
            float2 o; o.x = a0; o.y = a1;
            *(float2*)(partial + (size_t)t*NPIX + p) = o;
        }
    } else if (bid < 2028) {
        // ================= ZERO tail of delta_zs =================
        int z = (bid - 1984)*256 + tid;
        if (z < 11264) {
            int b = z / (11*512), rem = z % (11*512);
            out[(size_t)b*18*512 + 7*512 + rem] = 0.0f;
        }
    } else {
        // ================= LOSS_DELTA (1 block) =================
        float total = 0.0f;
        for (int r = 0; r < 14; r++) {
            float v0 = hB[r*512 + tid], v1 = hB[r*512 + 256 + tid];
            smem[tid] = v0*v0 + v1*v1; __syncthreads();
            for (int s = 128; s; s >>= 1) { if (tid < s) smem[tid] += smem[tid+s]; __syncthreads(); }
            if (tid == 0) total += sqrtf(smem[0]);
            __syncthreads();
        }
        if (tid == 0) out[OUT_LD] = total * (1.0f/14.0f);
    }
}

// ---------------- logits -> sigmoid -> segment partials ----------------
__global__ __launch_bounds__(256) void k_logits(
    const float* __restrict__ partial, const float* __restrict__ biasp,
    const float* __restrict__ alb, const int* __restrict__ choice,
    float* __restrict__ each, float* __restrict__ bsums, int* __restrict__ bcnts)
{
    __shared__ float ssum[20]; __shared__ int scnt[20]; __shared__ float sbias;
    int tid = threadIdx.x;
    if (tid < 20) { ssum[tid] = 0.0f; scnt[tid] = 0; }
    if (tid == 0) {
        float s = alb[0];
        for (int t = 0; t < 18; t++) s += biasp[t];
        sbias = s;
    }
    __syncthreads();
    int p = blockIdx.x*256 + tid;
    float lg = sbias;
    #pragma unroll
    for (int s = 0; s < 18; s++) lg += partial[(size_t)s*NPIX + p];
    float e = 1.0f / (1.0f + expf(-lg));
    each[p] = e;
    int ch = choice[p];
    atomicAdd(&ssum[ch], e);
    atomicAdd(&scnt[ch], 1);
    __syncthreads();
    if (tid < 20) { bsums[blockIdx.x*20 + tid] = ssum[tid]; bcnts[blockIdx.x*20 + tid] = scnt[tid]; }
}

// ---------------- final: stats (inline, redundant per block) + blur + loss_tv ----------------
__global__ __launch_bounds__(256) void k_final(
    const float* __restrict__ each, const int* __restrict__ choice,
    const float* __restrict__ bsums, const int* __restrict__ bcnts,
    float* __restrict__ out)
{
    __shared__ float av[20];
    __shared__ float regsh[20];
    __shared__ float red[256];
    int tid = threadIdx.x;
    if (tid < 20) {
        float s = 0.0f; int c = 0;
        for (int blk = 0; blk < 128; blk++) { s += bsums[blk*20 + tid]; c += bcnts[blk*20 + tid]; }
        float mean = s / fmaxf((float)c, 1.0f);
        av[tid] = (c > 0) ? mean : 1.0f;
        regsh[tid] = (c > 0) ? fmaxf(mean - 0.8f, 0.0f) : 0.0f;
    }
    __syncthreads();
    if (blockIdx.x == 0 && tid == 0) {
        float rs = 0.0f;
        for (int j = 0; j < 20; j++) rs += regsh[j];
        out[OUT_REG] = rs * 0.5f;
    }
    int p = blockIdx.x*256 + tid;
    int b = p >> 14, rem = p & 16383, y = rem >> 7, x = rem & 127;
    float k1[5]; float ks = 0.0f;
    #pragma unroll
    for (int i = 0; i < 5; i++) { float d = (float)(i-2) / 1.1f; k1[i] = expf(-0.5f*d*d); ks += k1[i]; }
    #pragma unroll
    for (int i = 0; i < 5; i++) k1[i] /= ks;
    const int* cb = choice + b*16384;
    float acc = 0.0f;
    #pragma unroll
    for (int a = 0; a < 5; a++) {
        int yy = y + a - 2; yy = (yy < 0) ? -yy : ((yy > 127) ? 254 - yy : yy);
        #pragma unroll
        for (int bb = 0; bb < 5; bb++) {
            int xx = x + bb - 2; xx = (xx < 0) ? -xx : ((xx > 127) ? 254 - xx : xx);
            float am = av[cb[yy*128 + xx]];
            float fin = (am < 0.8f) ? 0.0f : am;
            acc += k1[a]*k1[bb]*fin;
        }
    }
    out[OUT_BLUR + p] = acc;
    float amc = av[cb[y*128 + x]];
    float d = each[p] - amc;
    red[tid] = d*d; __syncthreads();
    for (int s = 128; s; s >>= 1) { if (tid < s) red[tid] += red[tid+s]; __syncthreads(); }
    if (tid == 0) atomicAdd(&out[OUT_TV], red[0] * (1.0f/32768.0f));
}

// ---------------- host ----------------
extern "C" void kernel_launch(void* const* d_in, const int* in_sizes, int n_in,
                              void* d_out, int out_size, void* d_ws, size_t ws_size,
                              hipStream_t stream)
{
    const float* x      = (const float*)d_in[0];
    const float* blend  = (const float*)d_in[11];   // fmap_10
    const float* mw     = (const float*)d_in[27];
    const float* mb     = (const float*)d_in[28];
    const float* afw    = (const float*)d_in[29];
    const float* afb    = (const float*)d_in[30];
    const float* aw     = (const float*)d_in[31];
    const float* ab     = (const float*)d_in[32];
    const float* alw    = (const float*)d_in[33];
    const float* alb    = (const float*)d_in[34];
    const float* istate = (const float*)d_in[35];
    float* out = (float*)d_out;
    float* ws  = (float*)d_ws;

    static const int LN[17] = {0,2,3,5,6,8,9,11,12,14,15,17,18,20,21,23,24};
    FPtrs fp;
    fp.f[0] = (const float*)d_in[26];               // fmap_25
    for (int c = 0; c < 17; c++) fp.f[1+c] = (const float*)d_in[1 + LN[c]];

    float* hA     = ws + WS_HA;
    float* hB     = ws + WS_HB;
    float* st     = ws + WS_ST;
    float* cn     = ws + WS_CN;
    float* biasp  = ws + WS_BIASP;
    float* v      = ws + WS_V;
    int*   choice = (int*)(ws + WS_CHOICE);
    float* part   = ws + WS_PART;
    float* each   = ws + WS_EACH;
    float* bsums  = ws + WS_SUMS;
    int*   bcnts  = (int*)(ws + WS_CNTS);

    k_pre<<<33, 512, 0, stream>>>(afw, afb, aw, ab, alw, istate, v, biasp, st, cn, x, hA, out);
    k_mlp<<<896, 256, 0, stream>>>(mw, mb, hA, hB, 0, nullptr);
    k_mlp<<<896, 256, 0, stream>>>(mw, mb, hB, hA, 1, nullptr);
    k_mlp<<<896, 256, 0, stream>>>(mw, mb, hA, hB, 2, out + OUT_DZ);
    k_mega<<<2029, 256, 0, stream>>>(fp, v, blend, st, cn, choice, part, hB, out);
    k_logits<<<128, 256, 0, stream>>>(part, biasp, alb, choice, each, bsums, bcnts);
    k_final<<<128, 256, 0, stream>>>(each, choice, bsums, bcnts, out);
}